// Round 3
// baseline (201.148 us; speedup 1.0000x reference)
//
#include <hip/hip_runtime.h>

// B=2, S=2048, D=1024, H=16, hd=64, SCALE=32.
// softmax over batch axis (B=2) == pointwise sigmoid((s0-s1)/32); no k-normalization.
// Sigmoid scale log2(e)/32 is folded into Q at the QKV-GEMM epilogue.
// NOTE: p1 must be 1-p0 (NOT p0*e): e=exp2(dS) overflows to inf -> 0*inf=NaN.
//
// R8: R7 showed occupancy 2->3 blocks/CU changed nothing (55.7 vs 56.2 us) ->
// per-tile critical path bound, with the Ps LDS round-trip (write+read+conflicts)
// on the path. Fix: PV via mfma_f32_16x16x16f16 with A=V^T (b64 from LDS) and
// B = sigmoid output REGISTERS directly (C-layout of QK == B-layout of K=16 MFMA).
// Ps deleted (LDS 52->32 KB, conflicts gone), V reads = conflict-free b64 via
// 16B-chunk XOR swizzle (cs ^= hd&3) applied on the pre-swizzled global source.
// Output lands transposed -> coalesced f16x4 vals stores.

typedef _Float16 f16;
typedef __attribute__((ext_vector_type(8))) _Float16 f16x8;
typedef __attribute__((ext_vector_type(4))) _Float16 f16x4;
typedef __attribute__((ext_vector_type(4))) float f32x4;

#define MFMA16(a,b,c)  __builtin_amdgcn_mfma_f32_16x16x32_f16(a,b,c,0,0,0)
#define MFMA16K(a,b,c) __builtin_amdgcn_mfma_f32_16x16x16f16(a,b,c,0,0,0)
#define GLD16(gp, lp) __builtin_amdgcn_global_load_lds(                         \
    (const __attribute__((address_space(1))) void*)(gp),                        \
    (__attribute__((address_space(3))) void*)(lp), 16, 0, 0)

// ---------------- fused prep: w transposes (blocks 0..1023) + x convert (1024..5119) ----------------
__global__ __launch_bounds__(256) void prep(const float* __restrict__ x,
                                            const float* __restrict__ w0, const float* __restrict__ w1,
                                            const float* __restrict__ w2, const float* __restrict__ w3,
                                            f16* __restrict__ xh,
                                            f16* __restrict__ o0, f16* __restrict__ o1,
                                            f16* __restrict__ o2, f16* __restrict__ o3) {
    const int bb = blockIdx.x;
    const int tid = threadIdx.x;
    if (bb >= 1024) {
        int i = (bb - 1024) * 256 + tid;
        float4 v = ((const float4*)x)[i];
        f16x4 h;
        h[0] = (f16)v.x; h[1] = (f16)v.y; h[2] = (f16)v.z; h[3] = (f16)v.w;
        *(f16x4*)(xh + (long)i * 4) = h;
        return;
    }
    const float* w; f16* o;
    switch (bb & 3) {
        case 0: w = w0; o = o0; break;
        case 1: w = w1; o = o1; break;
        case 2: w = w2; o = o2; break;
        default: w = w3; o = o3; break;
    }
    __shared__ alignas(16) f16 t[64][72];
    const int d0 = ((bb >> 2) & 15) * 64, j0 = (bb >> 6) * 64;
    #pragma unroll
    for (int it = 0; it < 4; ++it) {
        int idx = it * 256 + tid;
        int row = idx >> 4, c4 = idx & 15;
        float4 v = *(const float4*)(w + (long)(d0 + row) * 1024 + j0 + c4 * 4);
        f16x4 h;
        h[0] = (f16)v.x; h[1] = (f16)v.y; h[2] = (f16)v.z; h[3] = (f16)v.w;
        *(f16x4*)&t[row][c4 * 4] = h;
    }
    __syncthreads();
    #pragma unroll
    for (int it = 0; it < 4; ++it) {
        int idx = it * 256 + tid;
        int jr = idx >> 4, d4 = idx & 15;
        f16x4 h;
        #pragma unroll
        for (int m = 0; m < 4; ++m) h[m] = t[d4 * 4 + m][jr];
        *(f16x4*)(o + (long)(j0 + jr) * 1024 + d0 + d4 * 4) = h;
    }
}

// ---------------- fused QKV GEMM: [4096x1024] @ Wt^T, Wt = [wqT;wkT;wvT] [3072][1024] ----------------
// 128x128 tiles, grid(32,24) = 768 blocks = 3/CU. Q/K epilogue staged via LDS -> b128 stores.
__global__ __launch_bounds__(256, 1) void gemm_qkv(const f16* __restrict__ A,
                                                   const f16* __restrict__ Wt,
                                                   f16* __restrict__ Qg,
                                                   f16* __restrict__ Kg,
                                                   f16* __restrict__ Vtg) {
    __shared__ alignas(16) f16 smem[16384];          // As = [0:8192) 128x64, Bs = [8192:) 128x64
    f16* As = smem;
    f16* Bs = smem + 8192;
    const int tid = threadIdx.x;
    const int wave = tid >> 6, lane = tid & 63;
    const int l15 = lane & 15, lq = lane >> 4;
    const int sw = l15 & 7;
    const int m0 = blockIdx.x * 128, n0 = blockIdx.y * 128;
    const int wr = (wave >> 1) * 64, wc = (wave & 1) * 64;
    const int r8 = lane >> 3;
    const int swc8 = ((lane & 7) ^ r8) * 8;

    f32x4 acc[4][4] = {};

    for (int kt = 0; kt < 16; ++kt) {       // K = 1024, BK = 64
        __syncthreads();
        #pragma unroll
        for (int i = 0; i < 4; ++i) {
            GLD16(A  + (long)(m0 + wave * 32 + i * 8 + r8) * 1024 + kt * 64 + swc8, As + (wave * 32 + i * 8) * 64);
            GLD16(Wt + (long)(n0 + wave * 32 + i * 8 + r8) * 1024 + kt * 64 + swc8, Bs + (wave * 32 + i * 8) * 64);
        }
        __syncthreads();
        #pragma unroll
        for (int s2 = 0; s2 < 2; ++s2) {
            const int rc = ((s2 * 4 + lq) ^ sw) << 3;
            f16x8 af[4], bf[4];
            #pragma unroll
            for (int i = 0; i < 4; ++i) af[i] = *(const f16x8*)&As[(wr + i * 16 + l15) * 64 + rc];
            #pragma unroll
            for (int j = 0; j < 4; ++j) bf[j] = *(const f16x8*)&Bs[(wc + j * 16 + l15) * 64 + rc];
            #pragma unroll
            for (int i = 0; i < 4; ++i)
                #pragma unroll
                for (int j = 0; j < 4; ++j)
                    acc[i][j] = MFMA16(af[i], bf[j], acc[i][j]);
        }
    }

    const int sel = n0 >> 10;                       // 0:Q 1:K 2:V (block-uniform)
    const int nb = n0 - (sel << 10);

    if (sel < 2) {
        f16* dst = sel == 0 ? Qg : Kg;
        const float qs = sel == 0 ? 0.045084219f : 1.0f;   // log2(e)/32
        __syncthreads();
        #pragma unroll
        for (int i = 0; i < 4; ++i)
            #pragma unroll
            for (int j = 0; j < 4; ++j) {
                int row0 = wr + i * 16 + lq * 4;
                int colb = wc + j * 16 + l15;
                int chunk = colb >> 3, sub = colb & 7;
                #pragma unroll
                for (int r = 0; r < 4; ++r) {
                    int row = row0 + r;
                    smem[row * 128 + ((chunk ^ (row & 7)) << 3) + sub] = (f16)(acc[i][j][r] * qs);
                }
            }
        __syncthreads();
        #pragma unroll
        for (int e = 0; e < 8; ++e) {
            int id = e * 256 + tid;
            int row = id >> 4, c = id & 15;
            f16x8 v = *(const f16x8*)&smem[row * 128 + ((c ^ (row & 7)) << 3)];
            int gr = m0 + row, b = gr >> 11, s = gr & 2047;
            int gc = nb + c * 8, hh = gc >> 6, hd = gc & 63;
            *(f16x8*)(dst + (long)((b * 16 + hh) * 2048 + s) * 64 + hd) = v;
        }
    } else {
        #pragma unroll
        for (int i = 0; i < 4; ++i)
            #pragma unroll
            for (int j = 0; j < 4; ++j) {
                int gr0 = m0 + wr + i * 16 + lq * 4;
                int gc  = nb + wc + j * 16 + l15;
                int b = gr0 >> 11, s = gr0 & 2047;
                int hh = gc >> 6, hd = gc & 63;
                f16x4 v;
                #pragma unroll
                for (int r = 0; r < 4; ++r) v[r] = (f16)acc[i][j][r];
                *(f16x4*)(Vtg + (long)((b * 16 + hh) * 64 + hd) * 2048 + s) = v;
            }
    }
}

// ---------------- output GEMM: fp32 out = (vals0+..+valsN) @ woT^T ----------------
// BM=64, BN=128 -> grid(64,8) = 512 blocks = 2/CU.
template<int NSUM>
__global__ __launch_bounds__(256, 1) void gemm_out(const f16* __restrict__ A0,
                                                   const f16* __restrict__ A1,
                                                   const f16* __restrict__ A2,
                                                   const f16* __restrict__ A3,
                                                   const f16* __restrict__ Bt,
                                                   float* __restrict__ outp) {
    __shared__ alignas(16) f16 As[64][72];
    __shared__ alignas(16) f16 Bs[128][64];
    const int tid = threadIdx.x;
    const int wave = tid >> 6, lane = tid & 63;
    const int l15 = lane & 15, lq = lane >> 4;
    const int sw = l15 & 7;
    const int m0 = blockIdx.x * 64, n0 = blockIdx.y * 128;
    const int wr = (wave >> 1) * 32, wc = (wave & 1) * 64;
    const int r8 = lane >> 3;
    const int swc8 = ((lane & 7) ^ r8) * 8;

    f32x4 acc[2][4] = {};

    for (int kt = 0; kt < 16; ++kt) {
        __syncthreads();
        #pragma unroll
        for (int it = 0; it < 2; ++it) {
            int idx = it * 256 + tid;
            int row = idx >> 3, c = idx & 7;
            long off = (long)(m0 + row) * 1024 + kt * 64 + c * 8;
            f16x8 a = *(const f16x8*)(A0 + off) + *(const f16x8*)(A1 + off);
            if constexpr (NSUM == 4)
                a = a + *(const f16x8*)(A2 + off) + *(const f16x8*)(A3 + off);
            *(f16x8*)&As[row][c * 8] = a;
        }
        #pragma unroll
        for (int i = 0; i < 4; ++i)
            GLD16(Bt + (long)(n0 + wave * 32 + i * 8 + r8) * 1024 + kt * 64 + swc8, &Bs[wave * 32 + i * 8][0]);
        __syncthreads();
        #pragma unroll
        for (int s2 = 0; s2 < 2; ++s2) {
            const int rc = ((s2 * 4 + lq) ^ sw) << 3;
            f16x8 af[2], bf[4];
            #pragma unroll
            for (int i = 0; i < 2; ++i) af[i] = *(const f16x8*)&As[wr + i * 16 + l15][s2 * 32 + lq * 8];
            #pragma unroll
            for (int j = 0; j < 4; ++j) bf[j] = *(const f16x8*)&Bs[wc + j * 16 + l15][rc];
            #pragma unroll
            for (int i = 0; i < 2; ++i)
                #pragma unroll
                for (int j = 0; j < 4; ++j)
                    acc[i][j] = MFMA16(af[i], bf[j], acc[i][j]);
        }
    }

    #pragma unroll
    for (int i = 0; i < 2; ++i)
        #pragma unroll
        for (int j = 0; j < 4; ++j) {
            int gr0 = m0 + wr + i * 16 + lq * 4;
            int gc  = n0 + wc + j * 16 + l15;
            #pragma unroll
            for (int r = 0; r < 4; ++r)
                outp[(long)(gr0 + r) * 1024 + gc] = acc[i][j][r];
        }
}

// ---------------- fused batch-coupled attention, split-k x NS, K/V double-buffered ----------------
// K-tile = 32 keys. LDS = 32 KB. PV: O^T = V^T @ P^T via mfma 16x16x16, P fed straight
// from sigmoid registers (QK C-layout == K=16 B-operand layout) -- no P LDS round-trip.
// Vts 16B chunks XOR-swizzled by hd&3 (swizzle applied on global source; reads conflict-free b64).
__global__ __launch_bounds__(256, 3) void attention_kernel(const f16* __restrict__ Qg,
                                                           const f16* __restrict__ Kg,
                                                           const f16* __restrict__ Vtg,
                                                           f16* __restrict__ v0,
                                                           f16* __restrict__ v1,
                                                           f16* __restrict__ v2,
                                                           f16* __restrict__ v3) {
    __shared__ alignas(16) f16 Ks [2][2][32][64];    // [buf][batch][key][d]               16 KB
    __shared__ alignas(16) f16 Vts[2][2][64][32];    // [buf][batch][hd][key, chunk-swz]   16 KB
    const int tid = threadIdx.x;
    const int wave = tid >> 6, lane = tid & 63;
    const int l15 = lane & 15, lq = lane >> 4;
    const int sw  = l15 & 7;          // K-read XOR swizzle (128B rows)

    const int NS = gridDim.x >> 8;    // 4 (or 2 fallback)
    const int nt = 64 / NS;           // 32-key tiles per block
    const int bid = blockIdx.x;
    const int xcd = bid & 7, sl = bid >> 3;
    const int h  = xcd * 2 + (sl & 1);               // head pinned to XCD
    const int qt = (sl >> 1) & 15, ks = sl >> 5;
    const int q0 = qt * 128;
    const int key0 = ks * (nt << 5);
    f16* vals = ks == 0 ? v0 : ks == 1 ? v1 : ks == 2 ? v2 : v3;
    const int qr = q0 + wave * 32;

    f16x8 qfr[2][2][2];                              // Q pre-scaled by log2(e)/32
    #pragma unroll
    for (int b2 = 0; b2 < 2; ++b2)
        #pragma unroll
        for (int qq = 0; qq < 2; ++qq)
            #pragma unroll
            for (int s2 = 0; s2 < 2; ++s2)
                qfr[b2][qq][s2] = *(const f16x8*)(Qg + (long)((b2 * 16 + h) * 2048 + qr + qq * 16 + l15) * 64
                                                  + s2 * 32 + lq * 8);

    f32x4 acc[2][2][4] = {};                         // [batch][qq][hf]; D[row=hd][col=q]

    const int tb = wave & 1;
    const int r8 = lane >> 3;
    const int swc8 = ((lane & 7) ^ r8) * 8;
    const f16* kbase = Kg  + (long)((tb * 16 + h) * 2048 + key0) * 64 + r8 * 64 + swc8;
    // V staging: LDS chunk C=i*64+lane -> hd=C>>2, cs=C&3 holds keys (cs^(hd&3))*8..+7
    const f16* vbase = Vtg + (long)((tb * 16 + h) * 64 + (lane >> 2)) * 2048 + key0
                       + ((lane & 3) ^ ((lane >> 2) & 3)) * 8;

    auto stage = [&](int kt, int buf) {
        if (wave < 2) {
            const f16* g = kbase + kt * 2048;        // 32 keys x 64 halves
            f16* l = &Ks[buf][tb][0][0];
            #pragma unroll
            for (int i = 0; i < 4; ++i) GLD16(g + i * 512, l + i * 512);
        } else {
            const f16* g = vbase + kt * 32;
            f16* l = &Vts[buf][tb][0][0];
            #pragma unroll
            for (int i = 0; i < 4; ++i) GLD16(g + (long)i * 16 * 2048, l + i * 512);
        }
    };

    // per-lane V-read offset (halves): row l15 (hd&15), sub-b64 (lq&1), kf=0 chunk (lq>>1)^(l15&3).
    // kf flips chunk bit1 -> addr ^ 16. Read -> A[row=hd=hf*16+l15][k=lq*4+j] = V[key=kf*16+lq*4+j][hd].
    const int vro = l15 * 32 + (lq & 1) * 4 + ((((lq >> 1) ^ (l15 & 3))) << 3);
    const f16* VtsF = &Vts[0][0][0][0];

    stage(0, 0);
    for (int kt = 0; kt < nt; ++kt) {
        const int cur = kt & 1;
        __syncthreads();                             // publishes buf cur (loads issued last iter)
        if (kt < nt - 1) stage(kt + 1, cur ^ 1);     // prefetch next tile, drained next barrier

        f16x4 pp0[2][2], pp1[2][2];                  // [kf][qq]: P[q=l15][key=kf*16+lq*4+r]
        #pragma unroll
        for (int kf = 0; kf < 2; ++kf) {
            f32x4 S0[2] = {}, S1[2] = {};
            __builtin_amdgcn_s_setprio(1);
            #pragma unroll
            for (int s2 = 0; s2 < 2; ++s2) {
                const int rc = ((s2 * 4 + lq) ^ sw) << 3;
                f16x8 a0 = *(const f16x8*)&Ks[cur][0][kf * 16 + l15][rc];
                f16x8 a1 = *(const f16x8*)&Ks[cur][1][kf * 16 + l15][rc];
                #pragma unroll
                for (int qq = 0; qq < 2; ++qq) {
                    S0[qq] = MFMA16(a0, qfr[0][qq][s2], S0[qq]);
                    S1[qq] = MFMA16(a1, qfr[1][qq][s2], S1[qq]);
                }
            }
            __builtin_amdgcn_s_setprio(0);
            #pragma unroll
            for (int qq = 0; qq < 2; ++qq) {
                f16x4 p0v;
                #pragma unroll
                for (int r = 0; r < 4; ++r) {
                    float e = __builtin_amdgcn_exp2f(S1[qq][r] - S0[qq][r]);
                    float p = __builtin_amdgcn_rcpf(1.0f + e);                 // e=inf -> p=0 (safe)
                    p0v[r] = (f16)p;
                }
                f16x4 onev = {(f16)1.f, (f16)1.f, (f16)1.f, (f16)1.f};
                pp0[kf][qq] = p0v;
                pp1[kf][qq] = onev - p0v;                                      // packed f16 sub
            }
        }

        #pragma unroll
        for (int pb = 0; pb < 2; ++pb) {
            #pragma unroll
            for (int kf = 0; kf < 2; ++kf) {
                f16x4 vfrag[4];
                #pragma unroll
                for (int hf = 0; hf < 4; ++hf)
                    vfrag[hf] = *(const f16x4*)&VtsF[cur * 4096 + pb * 2048 + hf * 512
                                                     + (vro ^ (kf << 4))];
                __builtin_amdgcn_s_setprio(1);
                #pragma unroll
                for (int qq = 0; qq < 2; ++qq)
                    #pragma unroll
                    for (int hf = 0; hf < 4; ++hf)
                        acc[pb][qq][hf] = MFMA16K(vfrag[hf],
                                                  pb ? pp1[kf][qq] : pp0[kf][qq],
                                                  acc[pb][qq][hf]);
                __builtin_amdgcn_s_setprio(0);
            }
        }
    }

    // D[row=hd=hf*16+lq*4+r][col=q=qq*16+l15] -> coalesced f16x4 stores along hd
    #pragma unroll
    for (int pb = 0; pb < 2; ++pb)
        #pragma unroll
        for (int qq = 0; qq < 2; ++qq)
            #pragma unroll
            for (int hf = 0; hf < 4; ++hf) {
                f16x4 ov;
                #pragma unroll
                for (int r = 0; r < 4; ++r) ov[r] = (f16)acc[pb][qq][hf][r];
                *(f16x4*)(vals + (long)(pb * 2048 + qr + qq * 16 + l15) * 1024
                          + h * 64 + hf * 16 + lq * 4) = ov;
            }
}

extern "C" void kernel_launch(void* const* d_in, const int* in_sizes, int n_in,
                              void* d_out, int out_size, void* d_ws, size_t ws_size,
                              hipStream_t stream) {
    const float* x  = (const float*)d_in[0];
    const float* wq = (const float*)d_in[1];
    const float* wk = (const float*)d_in[2];
    const float* wv = (const float*)d_in[3];
    const float* wo = (const float*)d_in[4];

    char* ws = (char*)d_ws;
    f16* xh    = (f16*)(ws);                   // 8 MiB; dead after QKV gemm -> reused as vals0
    f16* wqT   = (f16*)(ws + 8388608);         // wqT,wkT,wvT contiguous = fused [3072][1024]
    f16* wkT   = (f16*)(ws + 10485760);
    f16* wvT   = (f16*)(ws + 12582912);
    f16* woT   = (f16*)(ws + 14680064);
    f16* Qg    = (f16*)(ws + 16777216);        // [2][16][2048][64] (pre-scaled by log2e/32)
    f16* Kg    = (f16*)(ws + 25165824);
    f16* Vtg   = (f16*)(ws + 33554432);        // [2][16][64][2048]
    f16* vals1 = (f16*)(ws + 41943040);
    f16* vals2 = (f16*)(ws + 50331648);        // only used when ws >= 64 MiB (split-k x4)
    f16* vals3 = (f16*)(ws + 58720256);
    f16* vals0 = xh;
    (void)in_sizes; (void)n_in; (void)out_size;

    const int NS = (ws_size >= (size_t)67108864) ? 4 : 2;   // split-k factor

    prep<<<5120, 256, 0, stream>>>(x, wq, wk, wv, wo, xh, wqT, wkT, wvT, woT);

    gemm_qkv<<<dim3(32, 24), 256, 0, stream>>>(xh, wqT, Qg, Kg, Vtg);

    attention_kernel<<<NS * 256, 256, 0, stream>>>(Qg, Kg, Vtg, vals0, vals1, vals2, vals3);

    if (NS == 4)
        gemm_out<4><<<dim3(64, 8), 256, 0, stream>>>(vals0, vals1, vals2, vals3, woT, (float*)d_out);
    else
        gemm_out<2><<<dim3(64, 8), 256, 0, stream>>>(vals0, vals1, vals0, vals0, woT, (float*)d_out);
}

// Round 4
// 193.982 us; speedup vs baseline: 1.0369x; 1.0369x over previous
//
#include <hip/hip_runtime.h>

// B=2, S=2048, D=1024, H=16, hd=64, SCALE=32.
// softmax over batch axis (B=2) == pointwise sigmoid((s0-s1)/32); no k-normalization.
// Sigmoid scale log2(e)/32 is folded into Q at the QKV-GEMM epilogue.
// NOTE: p1 must be 1-p0 (NOT p0*e): e=exp2(dS) overflows to inf -> 0*inf=NaN.
//
// R9: R8's +7M bank conflicts came from V-swizzle cs^=hd&3 (parity-coupled: only
// hd bit0 reaches the bank index for 64B rows -> 4-way in-phase). Fix: cs^=(hd>>1)&3.
// Also move QK and PV to mfma_f32_32x32x16_f16: 16 MFMAs/tile (was 48), all LDS
// reads b128 conflict-free. P stays in registers: cvt_pkrtz pairs + 2x
// v_permlane32_swap_b32 per key-half build the PV B-fragment (T12 primitive);
// p1 = 1-p0 applied after the permute.

typedef _Float16 f16;
typedef __attribute__((ext_vector_type(8))) _Float16 f16x8;
typedef __attribute__((ext_vector_type(4))) _Float16 f16x4;
typedef __attribute__((ext_vector_type(4))) float f32x4;
typedef __attribute__((ext_vector_type(16))) float f32x16;

#define MFMA16(a,b,c)  __builtin_amdgcn_mfma_f32_16x16x32_f16(a,b,c,0,0,0)
#define MFMA32(a,b,c)  __builtin_amdgcn_mfma_f32_32x32x16_f16(a,b,c,0,0,0)
#define GLD16(gp, lp) __builtin_amdgcn_global_load_lds(                         \
    (const __attribute__((address_space(1))) void*)(gp),                        \
    (__attribute__((address_space(3))) void*)(lp), 16, 0, 0)

// ---------------- fused prep: w transposes (blocks 0..1023) + x convert (1024..5119) ----------------
__global__ __launch_bounds__(256) void prep(const float* __restrict__ x,
                                            const float* __restrict__ w0, const float* __restrict__ w1,
                                            const float* __restrict__ w2, const float* __restrict__ w3,
                                            f16* __restrict__ xh,
                                            f16* __restrict__ o0, f16* __restrict__ o1,
                                            f16* __restrict__ o2, f16* __restrict__ o3) {
    const int bb = blockIdx.x;
    const int tid = threadIdx.x;
    if (bb >= 1024) {
        int i = (bb - 1024) * 256 + tid;
        float4 v = ((const float4*)x)[i];
        f16x4 h;
        h[0] = (f16)v.x; h[1] = (f16)v.y; h[2] = (f16)v.z; h[3] = (f16)v.w;
        *(f16x4*)(xh + (long)i * 4) = h;
        return;
    }
    const float* w; f16* o;
    switch (bb & 3) {
        case 0: w = w0; o = o0; break;
        case 1: w = w1; o = o1; break;
        case 2: w = w2; o = o2; break;
        default: w = w3; o = o3; break;
    }
    __shared__ alignas(16) f16 t[64][72];
    const int d0 = ((bb >> 2) & 15) * 64, j0 = (bb >> 6) * 64;
    #pragma unroll
    for (int it = 0; it < 4; ++it) {
        int idx = it * 256 + tid;
        int row = idx >> 4, c4 = idx & 15;
        float4 v = *(const float4*)(w + (long)(d0 + row) * 1024 + j0 + c4 * 4);
        f16x4 h;
        h[0] = (f16)v.x; h[1] = (f16)v.y; h[2] = (f16)v.z; h[3] = (f16)v.w;
        *(f16x4*)&t[row][c4 * 4] = h;
    }
    __syncthreads();
    #pragma unroll
    for (int it = 0; it < 4; ++it) {
        int idx = it * 256 + tid;
        int jr = idx >> 4, d4 = idx & 15;
        f16x4 h;
        #pragma unroll
        for (int m = 0; m < 4; ++m) h[m] = t[d4 * 4 + m][jr];
        *(f16x4*)(o + (long)(j0 + jr) * 1024 + d0 + d4 * 4) = h;
    }
}

// ---------------- fused QKV GEMM: [4096x1024] @ Wt^T, Wt = [wqT;wkT;wvT] [3072][1024] ----------------
__global__ __launch_bounds__(256, 1) void gemm_qkv(const f16* __restrict__ A,
                                                   const f16* __restrict__ Wt,
                                                   f16* __restrict__ Qg,
                                                   f16* __restrict__ Kg,
                                                   f16* __restrict__ Vtg) {
    __shared__ alignas(16) f16 smem[16384];          // As = [0:8192) 128x64, Bs = [8192:) 128x64
    f16* As = smem;
    f16* Bs = smem + 8192;
    const int tid = threadIdx.x;
    const int wave = tid >> 6, lane = tid & 63;
    const int l15 = lane & 15, lq = lane >> 4;
    const int sw = l15 & 7;
    const int m0 = blockIdx.x * 128, n0 = blockIdx.y * 128;
    const int wr = (wave >> 1) * 64, wc = (wave & 1) * 64;
    const int r8 = lane >> 3;
    const int swc8 = ((lane & 7) ^ r8) * 8;

    f32x4 acc[4][4] = {};

    for (int kt = 0; kt < 16; ++kt) {       // K = 1024, BK = 64
        __syncthreads();
        #pragma unroll
        for (int i = 0; i < 4; ++i) {
            GLD16(A  + (long)(m0 + wave * 32 + i * 8 + r8) * 1024 + kt * 64 + swc8, As + (wave * 32 + i * 8) * 64);
            GLD16(Wt + (long)(n0 + wave * 32 + i * 8 + r8) * 1024 + kt * 64 + swc8, Bs + (wave * 32 + i * 8) * 64);
        }
        __syncthreads();
        #pragma unroll
        for (int s2 = 0; s2 < 2; ++s2) {
            const int rc = ((s2 * 4 + lq) ^ sw) << 3;
            f16x8 af[4], bf[4];
            #pragma unroll
            for (int i = 0; i < 4; ++i) af[i] = *(const f16x8*)&As[(wr + i * 16 + l15) * 64 + rc];
            #pragma unroll
            for (int j = 0; j < 4; ++j) bf[j] = *(const f16x8*)&Bs[(wc + j * 16 + l15) * 64 + rc];
            #pragma unroll
            for (int i = 0; i < 4; ++i)
                #pragma unroll
                for (int j = 0; j < 4; ++j)
                    acc[i][j] = MFMA16(af[i], bf[j], acc[i][j]);
        }
    }

    const int sel = n0 >> 10;                       // 0:Q 1:K 2:V (block-uniform)
    const int nb = n0 - (sel << 10);

    if (sel < 2) {
        f16* dst = sel == 0 ? Qg : Kg;
        const float qs = sel == 0 ? 0.045084219f : 1.0f;   // log2(e)/32
        __syncthreads();
        #pragma unroll
        for (int i = 0; i < 4; ++i)
            #pragma unroll
            for (int j = 0; j < 4; ++j) {
                int row0 = wr + i * 16 + lq * 4;
                int colb = wc + j * 16 + l15;
                int chunk = colb >> 3, sub = colb & 7;
                #pragma unroll
                for (int r = 0; r < 4; ++r) {
                    int row = row0 + r;
                    smem[row * 128 + ((chunk ^ (row & 7)) << 3) + sub] = (f16)(acc[i][j][r] * qs);
                }
            }
        __syncthreads();
        #pragma unroll
        for (int e = 0; e < 8; ++e) {
            int id = e * 256 + tid;
            int row = id >> 4, c = id & 15;
            f16x8 v = *(const f16x8*)&smem[row * 128 + ((c ^ (row & 7)) << 3)];
            int gr = m0 + row, b = gr >> 11, s = gr & 2047;
            int gc = nb + c * 8, hh = gc >> 6, hd = gc & 63;
            *(f16x8*)(dst + (long)((b * 16 + hh) * 2048 + s) * 64 + hd) = v;
        }
    } else {
        #pragma unroll
        for (int i = 0; i < 4; ++i)
            #pragma unroll
            for (int j = 0; j < 4; ++j) {
                int gr0 = m0 + wr + i * 16 + lq * 4;
                int gc  = nb + wc + j * 16 + l15;
                int b = gr0 >> 11, s = gr0 & 2047;
                int hh = gc >> 6, hd = gc & 63;
                f16x4 v;
                #pragma unroll
                for (int r = 0; r < 4; ++r) v[r] = (f16)acc[i][j][r];
                *(f16x4*)(Vtg + (long)((b * 16 + hh) * 64 + hd) * 2048 + s) = v;
            }
    }
}

// ---------------- output GEMM: fp32 out = (vals0+..+valsN) @ woT^T ----------------
template<int NSUM>
__global__ __launch_bounds__(256, 1) void gemm_out(const f16* __restrict__ A0,
                                                   const f16* __restrict__ A1,
                                                   const f16* __restrict__ A2,
                                                   const f16* __restrict__ A3,
                                                   const f16* __restrict__ Bt,
                                                   float* __restrict__ outp) {
    __shared__ alignas(16) f16 As[64][72];
    __shared__ alignas(16) f16 Bs[128][64];
    const int tid = threadIdx.x;
    const int wave = tid >> 6, lane = tid & 63;
    const int l15 = lane & 15, lq = lane >> 4;
    const int sw = l15 & 7;
    const int m0 = blockIdx.x * 64, n0 = blockIdx.y * 128;
    const int wr = (wave >> 1) * 32, wc = (wave & 1) * 64;
    const int r8 = lane >> 3;
    const int swc8 = ((lane & 7) ^ r8) * 8;

    f32x4 acc[2][4] = {};

    for (int kt = 0; kt < 16; ++kt) {
        __syncthreads();
        #pragma unroll
        for (int it = 0; it < 2; ++it) {
            int idx = it * 256 + tid;
            int row = idx >> 3, c = idx & 7;
            long off = (long)(m0 + row) * 1024 + kt * 64 + c * 8;
            f16x8 a = *(const f16x8*)(A0 + off) + *(const f16x8*)(A1 + off);
            if constexpr (NSUM == 4)
                a = a + *(const f16x8*)(A2 + off) + *(const f16x8*)(A3 + off);
            *(f16x8*)&As[row][c * 8] = a;
        }
        #pragma unroll
        for (int i = 0; i < 4; ++i)
            GLD16(Bt + (long)(n0 + wave * 32 + i * 8 + r8) * 1024 + kt * 64 + swc8, &Bs[wave * 32 + i * 8][0]);
        __syncthreads();
        #pragma unroll
        for (int s2 = 0; s2 < 2; ++s2) {
            const int rc = ((s2 * 4 + lq) ^ sw) << 3;
            f16x8 af[2], bf[4];
            #pragma unroll
            for (int i = 0; i < 2; ++i) af[i] = *(const f16x8*)&As[wr + i * 16 + l15][s2 * 32 + lq * 8];
            #pragma unroll
            for (int j = 0; j < 4; ++j) bf[j] = *(const f16x8*)&Bs[wc + j * 16 + l15][rc];
            #pragma unroll
            for (int i = 0; i < 2; ++i)
                #pragma unroll
                for (int j = 0; j < 4; ++j)
                    acc[i][j] = MFMA16(af[i], bf[j], acc[i][j]);
        }
    }

    #pragma unroll
    for (int i = 0; i < 2; ++i)
        #pragma unroll
        for (int j = 0; j < 4; ++j) {
            int gr0 = m0 + wr + i * 16 + lq * 4;
            int gc  = n0 + wc + j * 16 + l15;
            #pragma unroll
            for (int r = 0; r < 4; ++r)
                outp[(long)(gr0 + r) * 1024 + gc] = acc[i][j][r];
        }
}

// ---------------- fused batch-coupled attention, split-k x NS, K/V double-buffered ----------------
// 32-key tiles, 32x32x16 MFMAs. LDS = 32 KB. QK: A=K rows (b128, row^7 chunk swz),
// B=Q regs. Sigmoid in regs; P-fragments built via cvt_pkrtz + permlane32_swap.
// PV: A=V^T rows (b128, (hd>>1)&3 chunk swz -- R8's hd&3 was parity-broken), B=P regs.
__global__ __launch_bounds__(256, 3) void attention_kernel(const f16* __restrict__ Qg,
                                                           const f16* __restrict__ Kg,
                                                           const f16* __restrict__ Vtg,
                                                           f16* __restrict__ v0,
                                                           f16* __restrict__ v1,
                                                           f16* __restrict__ v2,
                                                           f16* __restrict__ v3) {
    __shared__ alignas(16) f16 Ks [2][2][32][64];    // [buf][batch][key][d]               16 KB
    __shared__ alignas(16) f16 Vts[2][2][64][32];    // [buf][batch][hd][key, chunk-swz]   16 KB
    const int tid = threadIdx.x;
    const int wave = tid >> 6, lane = tid & 63;
    const int l31 = lane & 31, hi = lane >> 5;
    const int kchunk = l31 & 7;        // K-row (128B) chunk swizzle
    const int vcb = (l31 >> 1) & 3;    // V-row (64B) chunk swizzle: (hd>>1)&3

    const int NS = gridDim.x >> 8;     // 4 (or 2 fallback)
    const int nt = 64 / NS;            // 32-key tiles per block
    const int bid = blockIdx.x;
    const int xcd = bid & 7, sl = bid >> 3;
    const int h  = xcd * 2 + (sl & 1);               // head pinned to XCD
    const int qt = (sl >> 1) & 15, ks = sl >> 5;
    const int q0 = qt * 128;
    const int key0 = ks * (nt << 5);
    f16* vals = ks == 0 ? v0 : ks == 1 ? v1 : ks == 2 ? v2 : v3;
    const int qr = q0 + wave * 32;

    // Q fragments (B-operand of 32x32x16): B[k=hi*8+j][col=q=l31], d = s2*16 + hi*8 + j
    f16x8 qfr[2][4];
    #pragma unroll
    for (int b2 = 0; b2 < 2; ++b2)
        #pragma unroll
        for (int s2 = 0; s2 < 4; ++s2)
            qfr[b2][s2] = *(const f16x8*)(Qg + (long)((b2 * 16 + h) * 2048 + qr + l31) * 64
                                          + s2 * 16 + hi * 8);

    f32x16 acc[2][2] = {};                           // [batch][hdh]; D[row=hd][col=q]

    const int tb = wave & 1;
    const int r8 = lane >> 3;
    const int swc8 = ((lane & 7) ^ r8) * 8;
    const f16* kbase = Kg  + (long)((tb * 16 + h) * 2048 + key0) * 64 + r8 * 64 + swc8;
    // V staging: LDS chunk C=i*64+lane -> hd = i*16 + (lane>>2), phys cs = lane&3 holds
    // logical chunk (lane&3) ^ s, s = (hd>>1)&3 = (lane>>3)&3.
    const f16* vbase = Vtg + (long)((tb * 16 + h) * 64 + (lane >> 2)) * 2048 + key0
                       + ((lane & 3) ^ ((lane >> 3) & 3)) * 8;

    auto stage = [&](int kt, int buf) {
        if (wave < 2) {
            const f16* g = kbase + kt * 2048;        // 32 keys x 64 halves
            f16* l = &Ks[buf][tb][0][0];
            #pragma unroll
            for (int i = 0; i < 4; ++i) GLD16(g + i * 512, l + i * 512);
        } else {
            const f16* g = vbase + kt * 32;
            f16* l = &Vts[buf][tb][0][0];
            #pragma unroll
            for (int i = 0; i < 4; ++i) GLD16(g + (long)i * 16 * 2048, l + i * 512);
        }
    };

    const f16* VtsF = &Vts[0][0][0][0];
    const f16x8 ones8 = {(f16)1.f,(f16)1.f,(f16)1.f,(f16)1.f,(f16)1.f,(f16)1.f,(f16)1.f,(f16)1.f};

    stage(0, 0);
    for (int kt = 0; kt < nt; ++kt) {
        const int cur = kt & 1;
        __syncthreads();                             // publishes buf cur (loads issued last iter)
        if (kt < nt - 1) stage(kt + 1, cur ^ 1);     // prefetch next tile, drained next barrier

        // ---- QK^T: S[key=(r&3)+8(r>>2)+4hi][q=l31], both batches ----
        f32x16 S0 = {}, S1 = {};
        __builtin_amdgcn_s_setprio(1);
        #pragma unroll
        for (int s2 = 0; s2 < 4; ++s2) {
            const int rc = ((s2 * 2 + hi) ^ kchunk) << 3;
            f16x8 a0 = *(const f16x8*)&Ks[cur][0][l31][rc];
            f16x8 a1 = *(const f16x8*)&Ks[cur][1][l31][rc];
            S0 = MFMA32(a0, qfr[0][s2], S0);
            S1 = MFMA32(a1, qfr[1][s2], S1);
        }
        __builtin_amdgcn_s_setprio(0);

        // ---- batch-softmax sigmoid, packed to f16 pairs ----
        unsigned pk[8];
        #pragma unroll
        for (int p = 0; p < 8; ++p) {
            float e0 = __builtin_amdgcn_exp2f(S1[2 * p]     - S0[2 * p]);
            float e1 = __builtin_amdgcn_exp2f(S1[2 * p + 1] - S0[2 * p + 1]);
            float pa = __builtin_amdgcn_rcpf(1.0f + e0);     // e=inf -> p=0 (safe)
            float pb = __builtin_amdgcn_rcpf(1.0f + e1);
            auto h2 = __builtin_amdgcn_cvt_pkrtz(pa, pb);
            pk[p] = __builtin_bit_cast(unsigned, h2);
        }

        // ---- build PV B-fragments: B[k=hi*8+j][col=q], key = keyh*16 + hi*8 + j ----
        f16x8 pf0[2], pf1[2];
        #pragma unroll
        for (int keyh = 0; keyh < 2; ++keyh) {
            unsigned a0 = pk[4 * keyh + 0], b0 = pk[4 * keyh + 2];
            unsigned a1 = pk[4 * keyh + 1], b1 = pk[4 * keyh + 3];
            asm("v_permlane32_swap_b32 %0, %1" : "+v"(a0), "+v"(b0));
            asm("v_permlane32_swap_b32 %0, %1" : "+v"(a1), "+v"(b1));
            union { unsigned u[4]; f16x8 v; } m;
            m.u[0] = a0; m.u[1] = a1; m.u[2] = b0; m.u[3] = b1;
            pf0[keyh] = m.v;
            pf1[keyh] = ones8 - m.v;                 // NOT p0*e: 0*inf=NaN
        }

        // ---- PV: O^T[hd][q] += V^T[hd][key] * P^T[key][q] ----
        __builtin_amdgcn_s_setprio(1);
        #pragma unroll
        for (int pb = 0; pb < 2; ++pb)
            #pragma unroll
            for (int keyh = 0; keyh < 2; ++keyh) {
                const f16x8 pfr = pb ? pf1[keyh] : pf0[keyh];
                #pragma unroll
                for (int hdh = 0; hdh < 2; ++hdh) {
                    f16x8 vf = *(const f16x8*)&VtsF[cur * 4096 + pb * 2048 + hdh * 1024
                                                    + l31 * 32 + (((keyh * 2 + hi) ^ vcb) << 3)];
                    acc[pb][hdh] = MFMA32(vf, pfr, acc[pb][hdh]);
                }
            }
        __builtin_amdgcn_s_setprio(0);
    }

    // D[row=hd=hdh*32+g*8+hi*4+r2][col=q=l31] -> f16x4 stores along hd
    #pragma unroll
    for (int pb = 0; pb < 2; ++pb)
        #pragma unroll
        for (int hdh = 0; hdh < 2; ++hdh)
            #pragma unroll
            for (int g = 0; g < 4; ++g) {
                f16x4 ov;
                #pragma unroll
                for (int r2 = 0; r2 < 4; ++r2) ov[r2] = (f16)acc[pb][hdh][g * 4 + r2];
                *(f16x4*)(vals + (long)(pb * 2048 + qr + l31) * 1024
                          + h * 64 + hdh * 32 + g * 8 + hi * 4) = ov;
            }
}

extern "C" void kernel_launch(void* const* d_in, const int* in_sizes, int n_in,
                              void* d_out, int out_size, void* d_ws, size_t ws_size,
                              hipStream_t stream) {
    const float* x  = (const float*)d_in[0];
    const float* wq = (const float*)d_in[1];
    const float* wk = (const float*)d_in[2];
    const float* wv = (const float*)d_in[3];
    const float* wo = (const float*)d_in[4];

    char* ws = (char*)d_ws;
    f16* xh    = (f16*)(ws);                   // 8 MiB; dead after QKV gemm -> reused as vals0
    f16* wqT   = (f16*)(ws + 8388608);         // wqT,wkT,wvT contiguous = fused [3072][1024]
    f16* wkT   = (f16*)(ws + 10485760);
    f16* wvT   = (f16*)(ws + 12582912);
    f16* woT   = (f16*)(ws + 14680064);
    f16* Qg    = (f16*)(ws + 16777216);        // [2][16][2048][64] (pre-scaled by log2e/32)
    f16* Kg    = (f16*)(ws + 25165824);
    f16* Vtg   = (f16*)(ws + 33554432);        // [2][16][64][2048]
    f16* vals1 = (f16*)(ws + 41943040);
    f16* vals2 = (f16*)(ws + 50331648);        // only used when ws >= 64 MiB (split-k x4)
    f16* vals3 = (f16*)(ws + 58720256);
    f16* vals0 = xh;
    (void)in_sizes; (void)n_in; (void)out_size;

    const int NS = (ws_size >= (size_t)67108864) ? 4 : 2;   // split-k factor

    prep<<<5120, 256, 0, stream>>>(x, wq, wk, wv, wo, xh, wqT, wkT, wvT, woT);

    gemm_qkv<<<dim3(32, 24), 256, 0, stream>>>(xh, wqT, Qg, Kg, Vtg);

    attention_kernel<<<NS * 256, 256, 0, stream>>>(Qg, Kg, Vtg, vals0, vals1, vals2, vals3);

    if (NS == 4)
        gemm_out<4><<<dim3(64, 8), 256, 0, stream>>>(vals0, vals1, vals2, vals3, woT, (float*)d_out);
    else
        gemm_out<2><<<dim3(64, 8), 256, 0, stream>>>(vals0, vals1, vals0, vals0, woT, (float*)d_out);
}

// Round 5
// 192.877 us; speedup vs baseline: 1.0429x; 1.0057x over previous
//
#include <hip/hip_runtime.h>

// B=2, S=2048, D=1024, H=16, hd=64, SCALE=32.
// softmax over batch axis (B=2) == pointwise sigmoid((s0-s1)/32); no k-normalization.
// Sigmoid scale log2(e)/32 is folded into Q at the QKV-GEMM epilogue.
// NOTE: p1 must be 1-p0 (NOT p0*e): e=exp2(dS) overflows to inf -> 0*inf=NaN.
//
// R10: R5/R7/R9 all hit ~56 us with different inner loops -> dispatch+sync bound.
// (a) split-k x3: grid 768 = exactly 3 blocks/CU, ONE dispatch round (R9's 1024
//     blocks ran as 768 + 256-straggler round = 2x per-block time).
// (b) 3 LDS buffers, 2-deep prefetch, counted s_waitcnt vmcnt(4) + raw s_barrier
//     (m201 pattern) instead of __syncthreads' vmcnt(0) drain. Stage issued after
//     the barrier (its buffer's readers finished one iteration ago).

typedef _Float16 f16;
typedef __attribute__((ext_vector_type(8))) _Float16 f16x8;
typedef __attribute__((ext_vector_type(4))) _Float16 f16x4;
typedef __attribute__((ext_vector_type(4))) float f32x4;
typedef __attribute__((ext_vector_type(16))) float f32x16;

#define MFMA16(a,b,c)  __builtin_amdgcn_mfma_f32_16x16x32_f16(a,b,c,0,0,0)
#define MFMA32(a,b,c)  __builtin_amdgcn_mfma_f32_32x32x16_f16(a,b,c,0,0,0)
#define GLD16(gp, lp) __builtin_amdgcn_global_load_lds(                         \
    (const __attribute__((address_space(1))) void*)(gp),                        \
    (__attribute__((address_space(3))) void*)(lp), 16, 0, 0)

// ---------------- fused prep: w transposes (blocks 0..1023) + x convert (1024..5119) ----------------
__global__ __launch_bounds__(256) void prep(const float* __restrict__ x,
                                            const float* __restrict__ w0, const float* __restrict__ w1,
                                            const float* __restrict__ w2, const float* __restrict__ w3,
                                            f16* __restrict__ xh,
                                            f16* __restrict__ o0, f16* __restrict__ o1,
                                            f16* __restrict__ o2, f16* __restrict__ o3) {
    const int bb = blockIdx.x;
    const int tid = threadIdx.x;
    if (bb >= 1024) {
        int i = (bb - 1024) * 256 + tid;
        float4 v = ((const float4*)x)[i];
        f16x4 h;
        h[0] = (f16)v.x; h[1] = (f16)v.y; h[2] = (f16)v.z; h[3] = (f16)v.w;
        *(f16x4*)(xh + (long)i * 4) = h;
        return;
    }
    const float* w; f16* o;
    switch (bb & 3) {
        case 0: w = w0; o = o0; break;
        case 1: w = w1; o = o1; break;
        case 2: w = w2; o = o2; break;
        default: w = w3; o = o3; break;
    }
    __shared__ alignas(16) f16 t[64][72];
    const int d0 = ((bb >> 2) & 15) * 64, j0 = (bb >> 6) * 64;
    #pragma unroll
    for (int it = 0; it < 4; ++it) {
        int idx = it * 256 + tid;
        int row = idx >> 4, c4 = idx & 15;
        float4 v = *(const float4*)(w + (long)(d0 + row) * 1024 + j0 + c4 * 4);
        f16x4 h;
        h[0] = (f16)v.x; h[1] = (f16)v.y; h[2] = (f16)v.z; h[3] = (f16)v.w;
        *(f16x4*)&t[row][c4 * 4] = h;
    }
    __syncthreads();
    #pragma unroll
    for (int it = 0; it < 4; ++it) {
        int idx = it * 256 + tid;
        int jr = idx >> 4, d4 = idx & 15;
        f16x4 h;
        #pragma unroll
        for (int m = 0; m < 4; ++m) h[m] = t[d4 * 4 + m][jr];
        *(f16x4*)(o + (long)(j0 + jr) * 1024 + d0 + d4 * 4) = h;
    }
}

// ---------------- fused QKV GEMM: [4096x1024] @ Wt^T, Wt = [wqT;wkT;wvT] [3072][1024] ----------------
__global__ __launch_bounds__(256, 1) void gemm_qkv(const f16* __restrict__ A,
                                                   const f16* __restrict__ Wt,
                                                   f16* __restrict__ Qg,
                                                   f16* __restrict__ Kg,
                                                   f16* __restrict__ Vtg) {
    __shared__ alignas(16) f16 smem[16384];          // As = [0:8192) 128x64, Bs = [8192:) 128x64
    f16* As = smem;
    f16* Bs = smem + 8192;
    const int tid = threadIdx.x;
    const int wave = tid >> 6, lane = tid & 63;
    const int l15 = lane & 15, lq = lane >> 4;
    const int sw = l15 & 7;
    const int m0 = blockIdx.x * 128, n0 = blockIdx.y * 128;
    const int wr = (wave >> 1) * 64, wc = (wave & 1) * 64;
    const int r8 = lane >> 3;
    const int swc8 = ((lane & 7) ^ r8) * 8;

    f32x4 acc[4][4] = {};

    for (int kt = 0; kt < 16; ++kt) {       // K = 1024, BK = 64
        __syncthreads();
        #pragma unroll
        for (int i = 0; i < 4; ++i) {
            GLD16(A  + (long)(m0 + wave * 32 + i * 8 + r8) * 1024 + kt * 64 + swc8, As + (wave * 32 + i * 8) * 64);
            GLD16(Wt + (long)(n0 + wave * 32 + i * 8 + r8) * 1024 + kt * 64 + swc8, Bs + (wave * 32 + i * 8) * 64);
        }
        __syncthreads();
        #pragma unroll
        for (int s2 = 0; s2 < 2; ++s2) {
            const int rc = ((s2 * 4 + lq) ^ sw) << 3;
            f16x8 af[4], bf[4];
            #pragma unroll
            for (int i = 0; i < 4; ++i) af[i] = *(const f16x8*)&As[(wr + i * 16 + l15) * 64 + rc];
            #pragma unroll
            for (int j = 0; j < 4; ++j) bf[j] = *(const f16x8*)&Bs[(wc + j * 16 + l15) * 64 + rc];
            #pragma unroll
            for (int i = 0; i < 4; ++i)
                #pragma unroll
                for (int j = 0; j < 4; ++j)
                    acc[i][j] = MFMA16(af[i], bf[j], acc[i][j]);
        }
    }

    const int sel = n0 >> 10;                       // 0:Q 1:K 2:V (block-uniform)
    const int nb = n0 - (sel << 10);

    if (sel < 2) {
        f16* dst = sel == 0 ? Qg : Kg;
        const float qs = sel == 0 ? 0.045084219f : 1.0f;   // log2(e)/32
        __syncthreads();
        #pragma unroll
        for (int i = 0; i < 4; ++i)
            #pragma unroll
            for (int j = 0; j < 4; ++j) {
                int row0 = wr + i * 16 + lq * 4;
                int colb = wc + j * 16 + l15;
                int chunk = colb >> 3, sub = colb & 7;
                #pragma unroll
                for (int r = 0; r < 4; ++r) {
                    int row = row0 + r;
                    smem[row * 128 + ((chunk ^ (row & 7)) << 3) + sub] = (f16)(acc[i][j][r] * qs);
                }
            }
        __syncthreads();
        #pragma unroll
        for (int e = 0; e < 8; ++e) {
            int id = e * 256 + tid;
            int row = id >> 4, c = id & 15;
            f16x8 v = *(const f16x8*)&smem[row * 128 + ((c ^ (row & 7)) << 3)];
            int gr = m0 + row, b = gr >> 11, s = gr & 2047;
            int gc = nb + c * 8, hh = gc >> 6, hd = gc & 63;
            *(f16x8*)(dst + (long)((b * 16 + hh) * 2048 + s) * 64 + hd) = v;
        }
    } else {
        #pragma unroll
        for (int i = 0; i < 4; ++i)
            #pragma unroll
            for (int j = 0; j < 4; ++j) {
                int gr0 = m0 + wr + i * 16 + lq * 4;
                int gc  = nb + wc + j * 16 + l15;
                int b = gr0 >> 11, s = gr0 & 2047;
                int hh = gc >> 6, hd = gc & 63;
                f16x4 v;
                #pragma unroll
                for (int r = 0; r < 4; ++r) v[r] = (f16)acc[i][j][r];
                *(f16x4*)(Vtg + (long)((b * 16 + hh) * 64 + hd) * 2048 + s) = v;
            }
    }
}

// ---------------- output GEMM: fp32 out = (vals0+..+valsN) @ woT^T ----------------
template<int NSUM>
__global__ __launch_bounds__(256, 1) void gemm_out(const f16* __restrict__ A0,
                                                   const f16* __restrict__ A1,
                                                   const f16* __restrict__ A2,
                                                   const f16* __restrict__ A3,
                                                   const f16* __restrict__ Bt,
                                                   float* __restrict__ outp) {
    __shared__ alignas(16) f16 As[64][72];
    __shared__ alignas(16) f16 Bs[128][64];
    const int tid = threadIdx.x;
    const int wave = tid >> 6, lane = tid & 63;
    const int l15 = lane & 15, lq = lane >> 4;
    const int sw = l15 & 7;
    const int m0 = blockIdx.x * 64, n0 = blockIdx.y * 128;
    const int wr = (wave >> 1) * 32, wc = (wave & 1) * 64;
    const int r8 = lane >> 3;
    const int swc8 = ((lane & 7) ^ r8) * 8;

    f32x4 acc[2][4] = {};

    for (int kt = 0; kt < 16; ++kt) {
        __syncthreads();
        #pragma unroll
        for (int it = 0; it < 2; ++it) {
            int idx = it * 256 + tid;
            int row = idx >> 3, c = idx & 7;
            long off = (long)(m0 + row) * 1024 + kt * 64 + c * 8;
            f16x8 a = *(const f16x8*)(A0 + off) + *(const f16x8*)(A1 + off);
            if constexpr (NSUM >= 3) a = a + *(const f16x8*)(A2 + off);
            if constexpr (NSUM >= 4) a = a + *(const f16x8*)(A3 + off);
            *(f16x8*)&As[row][c * 8] = a;
        }
        #pragma unroll
        for (int i = 0; i < 4; ++i)
            GLD16(Bt + (long)(n0 + wave * 32 + i * 8 + r8) * 1024 + kt * 64 + swc8, &Bs[wave * 32 + i * 8][0]);
        __syncthreads();
        #pragma unroll
        for (int s2 = 0; s2 < 2; ++s2) {
            const int rc = ((s2 * 4 + lq) ^ sw) << 3;
            f16x8 af[2], bf[4];
            #pragma unroll
            for (int i = 0; i < 2; ++i) af[i] = *(const f16x8*)&As[wr + i * 16 + l15][s2 * 32 + lq * 8];
            #pragma unroll
            for (int j = 0; j < 4; ++j) bf[j] = *(const f16x8*)&Bs[wc + j * 16 + l15][rc];
            #pragma unroll
            for (int i = 0; i < 2; ++i)
                #pragma unroll
                for (int j = 0; j < 4; ++j)
                    acc[i][j] = MFMA16(af[i], bf[j], acc[i][j]);
        }
    }

    #pragma unroll
    for (int i = 0; i < 2; ++i)
        #pragma unroll
        for (int j = 0; j < 4; ++j) {
            int gr0 = m0 + wr + i * 16 + lq * 4;
            int gc  = n0 + wc + j * 16 + l15;
            #pragma unroll
            for (int r = 0; r < 4; ++r)
                outp[(long)(gr0 + r) * 1024 + gc] = acc[i][j][r];
        }
}

// ---------------- fused batch-coupled attention, split-k x NS, 3-buffer 2-deep pipeline ----------------
// 32-key tiles, 32x32x16 MFMAs, LDS 48 KB -> 3 blocks/CU. grid = NS*256 (NS=3 -> 768 =
// exactly 3/CU, single dispatch round). Counted vmcnt(4) + raw s_barrier: tile kt's
// loads issued 2 tiles ahead; stage after barrier (WAR-safe: that buf's readers done).
__global__ __launch_bounds__(256, 3) void attention_kernel(const f16* __restrict__ Qg,
                                                           const f16* __restrict__ Kg,
                                                           const f16* __restrict__ Vtg,
                                                           f16* __restrict__ v0,
                                                           f16* __restrict__ v1,
                                                           f16* __restrict__ v2) {
    __shared__ alignas(16) f16 Ks [3][2][32][64];    // [buf][batch][key][d]               24 KB
    __shared__ alignas(16) f16 Vts[3][2][64][32];    // [buf][batch][hd][key, chunk-swz]   24 KB
    const int tid = threadIdx.x;
    const int wave = tid >> 6, lane = tid & 63;
    const int l31 = lane & 31, hi = lane >> 5;
    const int kchunk = l31 & 7;        // K-row (128B) chunk swizzle
    const int vcb = (l31 >> 1) & 3;    // V-row (64B) chunk swizzle: (hd>>1)&3

    const int NS = gridDim.x >> 8;     // 3 (or 2 fallback)
    const int bid = blockIdx.x;
    const int xcd = bid & 7, sl = bid >> 3;
    const int h  = xcd * 2 + (sl & 1);               // head pinned to XCD
    const int qt = (sl >> 1) & 15, ks = sl >> 5;
    const int q0 = qt * 128;
    const int kb = 64 / NS, krem = 64 % NS;          // uneven split: e.g. 22/21/21
    const int nt = kb + (ks < krem ? 1 : 0);
    const int ts0 = ks * kb + (ks < krem ? ks : krem);
    const int key0 = ts0 * 32;
    f16* vals = ks == 0 ? v0 : ks == 1 ? v1 : v2;
    const int qr = q0 + wave * 32;

    // Q fragments (B-operand of 32x32x16): B[k=hi*8+j][col=q=l31], d = s2*16 + hi*8 + j
    f16x8 qfr[2][4];
    #pragma unroll
    for (int b2 = 0; b2 < 2; ++b2)
        #pragma unroll
        for (int s2 = 0; s2 < 4; ++s2)
            qfr[b2][s2] = *(const f16x8*)(Qg + (long)((b2 * 16 + h) * 2048 + qr + l31) * 64
                                          + s2 * 16 + hi * 8);

    f32x16 acc[2][2] = {};                           // [batch][hdh]; D[row=hd][col=q]

    const int tb = wave & 1;
    const int r8 = lane >> 3;
    const int swc8 = ((lane & 7) ^ r8) * 8;
    const f16* kbase = Kg  + (long)((tb * 16 + h) * 2048 + key0) * 64 + r8 * 64 + swc8;
    // V staging: LDS chunk C=i*64+lane -> hd = i*16 + (lane>>2), phys cs = lane&3 holds
    // logical chunk (lane&3) ^ s, s = (hd>>1)&3 = (lane>>3)&3.
    const f16* vbase = Vtg + (long)((tb * 16 + h) * 64 + (lane >> 2)) * 2048 + key0
                       + ((lane & 3) ^ ((lane >> 3) & 3)) * 8;

    auto stage = [&](int kt, int buf) {              // exactly 4 GLD16 per wave
        if (wave < 2) {
            const f16* g = kbase + kt * 2048;        // 32 keys x 64 halves
            f16* l = &Ks[buf][tb][0][0];
            #pragma unroll
            for (int i = 0; i < 4; ++i) GLD16(g + i * 512, l + i * 512);
        } else {
            const f16* g = vbase + kt * 32;
            f16* l = &Vts[buf][tb][0][0];
            #pragma unroll
            for (int i = 0; i < 4; ++i) GLD16(g + (long)i * 16 * 2048, l + i * 512);
        }
    };

    const f16* VtsF = &Vts[0][0][0][0];
    const f16x8 ones8 = {(f16)1.f,(f16)1.f,(f16)1.f,(f16)1.f,(f16)1.f,(f16)1.f,(f16)1.f,(f16)1.f};

    stage(0, 0);
    stage(1, 1);
    int cur = 0, nx2 = 2;
    for (int kt = 0; kt < nt; ++kt) {
        // tile kt's loads were issued 2 iterations ago; 4 newer (kt+1) may stay in flight
        if (kt == nt - 1) asm volatile("s_waitcnt vmcnt(0)" ::: "memory");
        else              asm volatile("s_waitcnt vmcnt(4)" ::: "memory");
        __builtin_amdgcn_s_barrier();
        __builtin_amdgcn_sched_barrier(0);
        if (kt + 2 < nt) stage(kt + 2, nx2);         // overwrites buf read at kt-1: safe past barrier

        // ---- QK^T: S[key=(r&3)+8(r>>2)+4hi][q=l31], both batches ----
        f32x16 S0 = {}, S1 = {};
        __builtin_amdgcn_s_setprio(1);
        #pragma unroll
        for (int s2 = 0; s2 < 4; ++s2) {
            const int rc = ((s2 * 2 + hi) ^ kchunk) << 3;
            f16x8 a0 = *(const f16x8*)&Ks[cur][0][l31][rc];
            f16x8 a1 = *(const f16x8*)&Ks[cur][1][l31][rc];
            S0 = MFMA32(a0, qfr[0][s2], S0);
            S1 = MFMA32(a1, qfr[1][s2], S1);
        }
        __builtin_amdgcn_s_setprio(0);

        // ---- batch-softmax sigmoid, packed to f16 pairs ----
        unsigned pk[8];
        #pragma unroll
        for (int p = 0; p < 8; ++p) {
            float e0 = __builtin_amdgcn_exp2f(S1[2 * p]     - S0[2 * p]);
            float e1 = __builtin_amdgcn_exp2f(S1[2 * p + 1] - S0[2 * p + 1]);
            float pa = __builtin_amdgcn_rcpf(1.0f + e0);     // e=inf -> p=0 (safe)
            float pb = __builtin_amdgcn_rcpf(1.0f + e1);
            auto h2 = __builtin_amdgcn_cvt_pkrtz(pa, pb);
            pk[p] = __builtin_bit_cast(unsigned, h2);
        }

        // ---- build PV B-fragments: B[k=hi*8+j][col=q], key = keyh*16 + hi*8 + j ----
        f16x8 pf0[2], pf1[2];
        #pragma unroll
        for (int keyh = 0; keyh < 2; ++keyh) {
            unsigned a0 = pk[4 * keyh + 0], b0 = pk[4 * keyh + 2];
            unsigned a1 = pk[4 * keyh + 1], b1 = pk[4 * keyh + 3];
            asm("v_permlane32_swap_b32 %0, %1" : "+v"(a0), "+v"(b0));
            asm("v_permlane32_swap_b32 %0, %1" : "+v"(a1), "+v"(b1));
            union { unsigned u[4]; f16x8 v; } m;
            m.u[0] = a0; m.u[1] = a1; m.u[2] = b0; m.u[3] = b1;
            pf0[keyh] = m.v;
            pf1[keyh] = ones8 - m.v;                 // NOT p0*e: 0*inf=NaN
        }

        // ---- PV: O^T[hd][q] += V^T[hd][key] * P^T[key][q] ----
        __builtin_amdgcn_s_setprio(1);
        #pragma unroll
        for (int pb = 0; pb < 2; ++pb)
            #pragma unroll
            for (int keyh = 0; keyh < 2; ++keyh) {
                const f16x8 pfr = pb ? pf1[keyh] : pf0[keyh];
                #pragma unroll
                for (int hdh = 0; hdh < 2; ++hdh) {
                    f16x8 vf = *(const f16x8*)&VtsF[cur * 4096 + pb * 2048 + hdh * 1024
                                                    + l31 * 32 + (((keyh * 2 + hi) ^ vcb) << 3)];
                    acc[pb][hdh] = MFMA32(vf, pfr, acc[pb][hdh]);
                }
            }
        __builtin_amdgcn_s_setprio(0);

        cur = cur == 2 ? 0 : cur + 1;
        nx2 = nx2 == 2 ? 0 : nx2 + 1;
    }

    // D[row=hd=hdh*32+g*8+hi*4+r2][col=q=l31] -> f16x4 stores along hd
    #pragma unroll
    for (int pb = 0; pb < 2; ++pb)
        #pragma unroll
        for (int hdh = 0; hdh < 2; ++hdh)
            #pragma unroll
            for (int g = 0; g < 4; ++g) {
                f16x4 ov;
                #pragma unroll
                for (int r2 = 0; r2 < 4; ++r2) ov[r2] = (f16)acc[pb][hdh][g * 4 + r2];
                *(f16x4*)(vals + (long)(pb * 2048 + qr + l31) * 1024
                          + h * 64 + hdh * 32 + g * 8 + hi * 4) = ov;
            }
}

extern "C" void kernel_launch(void* const* d_in, const int* in_sizes, int n_in,
                              void* d_out, int out_size, void* d_ws, size_t ws_size,
                              hipStream_t stream) {
    const float* x  = (const float*)d_in[0];
    const float* wq = (const float*)d_in[1];
    const float* wk = (const float*)d_in[2];
    const float* wv = (const float*)d_in[3];
    const float* wo = (const float*)d_in[4];

    char* ws = (char*)d_ws;
    f16* xh    = (f16*)(ws);                   // 8 MiB; dead after QKV gemm -> reused as vals0
    f16* wqT   = (f16*)(ws + 8388608);         // wqT,wkT,wvT contiguous = fused [3072][1024]
    f16* wkT   = (f16*)(ws + 10485760);
    f16* wvT   = (f16*)(ws + 12582912);
    f16* woT   = (f16*)(ws + 14680064);
    f16* Qg    = (f16*)(ws + 16777216);        // [2][16][2048][64] (pre-scaled by log2e/32)
    f16* Kg    = (f16*)(ws + 25165824);
    f16* Vtg   = (f16*)(ws + 33554432);        // [2][16][64][2048]
    f16* vals1 = (f16*)(ws + 41943040);
    f16* vals2 = (f16*)(ws + 50331648);        // needs ws >= 56 MiB for split-k x3
    f16* vals0 = xh;
    (void)in_sizes; (void)n_in; (void)out_size;

    const int NS = (ws_size >= (size_t)58720256) ? 3 : 2;   // split-k factor

    prep<<<5120, 256, 0, stream>>>(x, wq, wk, wv, wo, xh, wqT, wkT, wvT, woT);

    gemm_qkv<<<dim3(32, 24), 256, 0, stream>>>(xh, wqT, Qg, Kg, Vtg);

    attention_kernel<<<NS * 256, 256, 0, stream>>>(Qg, Kg, Vtg, vals0, vals1, vals2);

    if (NS == 3)
        gemm_out<3><<<dim3(64, 8), 256, 0, stream>>>(vals0, vals1, vals2, vals0, woT, (float*)d_out);
    else
        gemm_out<2><<<dim3(64, 8), 256, 0, stream>>>(vals0, vals1, vals0, vals0, woT, (float*)d_out);
}

// Round 7
// 191.325 us; speedup vs baseline: 1.0513x; 1.0081x over previous
//
#include <hip/hip_runtime.h>

// B=2, S=2048, D=1024, H=16, hd=64, SCALE=32.
// softmax over batch axis (B=2) == pointwise sigmoid((s1-s0)/32); no k-normalization.
// Sigmoid scale log2(e)/32 is folded into Q at the QKV-GEMM epilogue.
// NOTE: p1 must be 1-p0 (NOT p0*e): e=exp2(dS) overflows to inf -> 0*inf=NaN.
//
// R12 = R11 with two address bugs fixed:
//  (1) K staging had a stray "- ((lane&15)<<3)" in the global address;
//  (2) V read used per-buffer stride 8192, actual Vts stride is 4096 halves
//      (cur=2 read 32KB past the array).
// Design (R11): per-CU LDS read volume only shrinks with q-per-wave. q=64/wave
// (acc 128 AGPR), grid 512 = 2 blocks/CU single round. Batch-concat trick:
// attention only needs dS = S1-S0, so Kc = [K1 | -K0], Qc = [Q1 | Q0] gives dS
// in ONE K=128 MFMA chain (S regs halve, subs vanish). V frags shared across
// both q-halves (-25% LDS reads); per-CU wave-iterations halve.

typedef _Float16 f16;
typedef __attribute__((ext_vector_type(8))) _Float16 f16x8;
typedef __attribute__((ext_vector_type(4))) _Float16 f16x4;
typedef __attribute__((ext_vector_type(4))) float f32x4;
typedef __attribute__((ext_vector_type(16))) float f32x16;

#define MFMA16(a,b,c)  __builtin_amdgcn_mfma_f32_16x16x32_f16(a,b,c,0,0,0)
#define MFMA32(a,b,c)  __builtin_amdgcn_mfma_f32_32x32x16_f16(a,b,c,0,0,0)
#define GLD16(gp, lp) __builtin_amdgcn_global_load_lds(                         \
    (const __attribute__((address_space(1))) void*)(gp),                        \
    (__attribute__((address_space(3))) void*)(lp), 16, 0, 0)

// ---------------- fused prep: w transposes (blocks 0..1023) + x convert (1024..5119) ----------------
__global__ __launch_bounds__(256) void prep(const float* __restrict__ x,
                                            const float* __restrict__ w0, const float* __restrict__ w1,
                                            const float* __restrict__ w2, const float* __restrict__ w3,
                                            f16* __restrict__ xh,
                                            f16* __restrict__ o0, f16* __restrict__ o1,
                                            f16* __restrict__ o2, f16* __restrict__ o3) {
    const int bb = blockIdx.x;
    const int tid = threadIdx.x;
    if (bb >= 1024) {
        int i = (bb - 1024) * 256 + tid;
        float4 v = ((const float4*)x)[i];
        f16x4 h;
        h[0] = (f16)v.x; h[1] = (f16)v.y; h[2] = (f16)v.z; h[3] = (f16)v.w;
        *(f16x4*)(xh + (long)i * 4) = h;
        return;
    }
    const float* w; f16* o;
    switch (bb & 3) {
        case 0: w = w0; o = o0; break;
        case 1: w = w1; o = o1; break;
        case 2: w = w2; o = o2; break;
        default: w = w3; o = o3; break;
    }
    __shared__ alignas(16) f16 t[64][72];
    const int d0 = ((bb >> 2) & 15) * 64, j0 = (bb >> 6) * 64;
    #pragma unroll
    for (int it = 0; it < 4; ++it) {
        int idx = it * 256 + tid;
        int row = idx >> 4, c4 = idx & 15;
        float4 v = *(const float4*)(w + (long)(d0 + row) * 1024 + j0 + c4 * 4);
        f16x4 h;
        h[0] = (f16)v.x; h[1] = (f16)v.y; h[2] = (f16)v.z; h[3] = (f16)v.w;
        *(f16x4*)&t[row][c4 * 4] = h;
    }
    __syncthreads();
    #pragma unroll
    for (int it = 0; it < 4; ++it) {
        int idx = it * 256 + tid;
        int jr = idx >> 4, d4 = idx & 15;
        f16x4 h;
        #pragma unroll
        for (int m = 0; m < 4; ++m) h[m] = t[d4 * 4 + m][jr];
        *(f16x4*)(o + (long)(j0 + jr) * 1024 + d0 + d4 * 4) = h;
    }
}

// ---------------- fused QKV GEMM: [4096x1024] @ Wt^T, Wt = [wqT;wkT;wvT] [3072][1024] ----------------
// Epilogue: Q/K written into batch-concat layouts Qc/Kc [16][2048][128]:
// d 0..63 = batch1, d 64..127 = batch0; K batch0 negated; Q scaled by log2(e)/32.
__global__ __launch_bounds__(256, 1) void gemm_qkv(const f16* __restrict__ A,
                                                   const f16* __restrict__ Wt,
                                                   f16* __restrict__ Qc,
                                                   f16* __restrict__ Kc,
                                                   f16* __restrict__ Vtg) {
    __shared__ alignas(16) f16 smem[16384];          // As = [0:8192) 128x64, Bs = [8192:) 128x64
    f16* As = smem;
    f16* Bs = smem + 8192;
    const int tid = threadIdx.x;
    const int wave = tid >> 6, lane = tid & 63;
    const int l15 = lane & 15, lq = lane >> 4;
    const int sw = l15 & 7;
    const int m0 = blockIdx.x * 128, n0 = blockIdx.y * 128;
    const int wr = (wave >> 1) * 64, wc = (wave & 1) * 64;
    const int r8 = lane >> 3;
    const int swc8 = ((lane & 7) ^ r8) * 8;

    f32x4 acc[4][4] = {};

    for (int kt = 0; kt < 16; ++kt) {       // K = 1024, BK = 64
        __syncthreads();
        #pragma unroll
        for (int i = 0; i < 4; ++i) {
            GLD16(A  + (long)(m0 + wave * 32 + i * 8 + r8) * 1024 + kt * 64 + swc8, As + (wave * 32 + i * 8) * 64);
            GLD16(Wt + (long)(n0 + wave * 32 + i * 8 + r8) * 1024 + kt * 64 + swc8, Bs + (wave * 32 + i * 8) * 64);
        }
        __syncthreads();
        #pragma unroll
        for (int s2 = 0; s2 < 2; ++s2) {
            const int rc = ((s2 * 4 + lq) ^ sw) << 3;
            f16x8 af[4], bf[4];
            #pragma unroll
            for (int i = 0; i < 4; ++i) af[i] = *(const f16x8*)&As[(wr + i * 16 + l15) * 64 + rc];
            #pragma unroll
            for (int j = 0; j < 4; ++j) bf[j] = *(const f16x8*)&Bs[(wc + j * 16 + l15) * 64 + rc];
            #pragma unroll
            for (int i = 0; i < 4; ++i)
                #pragma unroll
                for (int j = 0; j < 4; ++j)
                    acc[i][j] = MFMA16(af[i], bf[j], acc[i][j]);
        }
    }

    const int sel = n0 >> 10;                       // 0:Q 1:K 2:V (block-uniform)
    const int nb = n0 - (sel << 10);

    if (sel < 2) {
        f16* dst = sel == 0 ? Qc : Kc;
        const int b = m0 >> 11;                            // block-uniform batch
        const int boff = b ? 0 : 64;                       // batch1 -> d 0..63, batch0 -> 64..127
        const float qs = sel == 0 ? 0.045084219f           // log2(e)/32
                                  : (b == 0 ? -1.0f : 1.0f);  // negate K batch0
        __syncthreads();
        #pragma unroll
        for (int i = 0; i < 4; ++i)
            #pragma unroll
            for (int j = 0; j < 4; ++j) {
                int row0 = wr + i * 16 + lq * 4;
                int colb = wc + j * 16 + l15;
                int chunk = colb >> 3, sub = colb & 7;
                #pragma unroll
                for (int r = 0; r < 4; ++r) {
                    int row = row0 + r;
                    smem[row * 128 + ((chunk ^ (row & 7)) << 3) + sub] = (f16)(acc[i][j][r] * qs);
                }
            }
        __syncthreads();
        #pragma unroll
        for (int e = 0; e < 8; ++e) {
            int id = e * 256 + tid;
            int row = id >> 4, c = id & 15;
            f16x8 v = *(const f16x8*)&smem[row * 128 + ((c ^ (row & 7)) << 3)];
            int gr = m0 + row, s = gr & 2047;
            int gc = nb + c * 8, hh = gc >> 6, hd = gc & 63;
            *(f16x8*)(dst + (long)(hh * 2048 + s) * 128 + boff + hd) = v;
        }
    } else {
        #pragma unroll
        for (int i = 0; i < 4; ++i)
            #pragma unroll
            for (int j = 0; j < 4; ++j) {
                int gr0 = m0 + wr + i * 16 + lq * 4;
                int gc  = nb + wc + j * 16 + l15;
                int b = gr0 >> 11, s = gr0 & 2047;
                int hh = gc >> 6, hd = gc & 63;
                f16x4 v;
                #pragma unroll
                for (int r = 0; r < 4; ++r) v[r] = (f16)acc[i][j][r];
                *(f16x4*)(Vtg + (long)((b * 16 + hh) * 64 + hd) * 2048 + s) = v;
            }
    }
}

// ---------------- output GEMM: fp32 out = (vals0+..+valsN) @ woT^T ----------------
template<int NSUM>
__global__ __launch_bounds__(256, 1) void gemm_out(const f16* __restrict__ A0,
                                                   const f16* __restrict__ A1,
                                                   const f16* __restrict__ A2,
                                                   const f16* __restrict__ A3,
                                                   const f16* __restrict__ Bt,
                                                   float* __restrict__ outp) {
    __shared__ alignas(16) f16 As[64][72];
    __shared__ alignas(16) f16 Bs[128][64];
    const int tid = threadIdx.x;
    const int wave = tid >> 6, lane = tid & 63;
    const int l15 = lane & 15, lq = lane >> 4;
    const int sw = l15 & 7;
    const int m0 = blockIdx.x * 64, n0 = blockIdx.y * 128;
    const int wr = (wave >> 1) * 32, wc = (wave & 1) * 64;
    const int r8 = lane >> 3;
    const int swc8 = ((lane & 7) ^ r8) * 8;

    f32x4 acc[2][4] = {};

    for (int kt = 0; kt < 16; ++kt) {
        __syncthreads();
        #pragma unroll
        for (int it = 0; it < 2; ++it) {
            int idx = it * 256 + tid;
            int row = idx >> 3, c = idx & 7;
            long off = (long)(m0 + row) * 1024 + kt * 64 + c * 8;
            f16x8 a = *(const f16x8*)(A0 + off) + *(const f16x8*)(A1 + off);
            if constexpr (NSUM >= 3) a = a + *(const f16x8*)(A2 + off);
            if constexpr (NSUM >= 4) a = a + *(const f16x8*)(A3 + off);
            *(f16x8*)&As[row][c * 8] = a;
        }
        #pragma unroll
        for (int i = 0; i < 4; ++i)
            GLD16(Bt + (long)(n0 + wave * 32 + i * 8 + r8) * 1024 + kt * 64 + swc8, &Bs[wave * 32 + i * 8][0]);
        __syncthreads();
        #pragma unroll
        for (int s2 = 0; s2 < 2; ++s2) {
            const int rc = ((s2 * 4 + lq) ^ sw) << 3;
            f16x8 af[2], bf[4];
            #pragma unroll
            for (int i = 0; i < 2; ++i) af[i] = *(const f16x8*)&As[wr + i * 16 + l15][s2 * 32 + lq * 8];
            #pragma unroll
            for (int j = 0; j < 4; ++j) bf[j] = *(const f16x8*)&Bs[wc + j * 16 + l15][rc];
            #pragma unroll
            for (int i = 0; i < 2; ++i)
                #pragma unroll
                for (int j = 0; j < 4; ++j)
                    acc[i][j] = MFMA16(af[i], bf[j], acc[i][j]);
        }
    }

    #pragma unroll
    for (int i = 0; i < 2; ++i)
        #pragma unroll
        for (int j = 0; j < 4; ++j) {
            int gr0 = m0 + wr + i * 16 + lq * 4;
            int gc  = n0 + wc + j * 16 + l15;
            #pragma unroll
            for (int r = 0; r < 4; ++r)
                outp[(long)(gr0 + r) * 1024 + gc] = acc[i][j][r];
        }
}

// ---------------- fused batch-coupled attention: q=64/wave, concat-K dS, split-k x4 ----------------
// 32-key tiles, 3 LDS buffers, 2-deep prefetch, counted vmcnt(4). LDS 48 KB.
// grid 512 (16h x 8qt x 4ks) = 2 blocks/CU. KsC rows = [K1 | -K0] (256B, chunk-XOR
// by row&15, both sides); Vts per-batch as R10. QK: one K=128 chain -> dS directly.
__global__ __launch_bounds__(256, 2) void attention_kernel(const f16* __restrict__ Qc,
                                                           const f16* __restrict__ Kc,
                                                           const f16* __restrict__ Vtg,
                                                           f16* __restrict__ v0,
                                                           f16* __restrict__ v1,
                                                           f16* __restrict__ v2,
                                                           f16* __restrict__ v3) {
    __shared__ alignas(16) f16 KsC[3][32][128];      // [buf][key][dc]  24 KB
    __shared__ alignas(16) f16 Vts[3][2][64][32];    // [buf][batch][hd][key-swz] 24 KB
    const int tid = threadIdx.x;
    const int wave = tid >> 6, lane = tid & 63;
    const int l31 = lane & 31, hi = lane >> 5;
    const int kch = l31 & 15;          // K-row (256B) chunk swizzle
    const int vcb = (l31 >> 1) & 3;    // V-row (64B) chunk swizzle

    const int bid = blockIdx.x;
    const int xcd = bid & 7, sl = bid >> 3;
    const int h  = xcd * 2 + (sl & 1);               // head pinned to XCD
    const int qt = (sl >> 1) & 7, ks = sl >> 4;
    const int q0 = qt * 256;
    const int key0 = ks * 512;                       // 16 tiles of 32 keys per split
    const int nt = 16;
    f16* vals = ks == 0 ? v0 : ks == 1 ? v1 : ks == 2 ? v2 : v3;
    const int qr = q0 + wave * 64;

    // Qc fragments (B-operand): [g][s2], d-chunk = s2*16 + hi*8, col q = qr + g*32 + l31
    f16x8 qfr[2][8];
    #pragma unroll
    for (int g = 0; g < 2; ++g)
        #pragma unroll
        for (int s2 = 0; s2 < 8; ++s2)
            qfr[g][s2] = *(const f16x8*)(Qc + (long)(h * 2048 + qr + g * 32 + l31) * 128
                                         + s2 * 16 + hi * 8);

    f32x16 acc[2][2][2] = {};                        // [pb][g][hdh]; D[row=hd][col=q]

    // K staging (waves 0,1): rows kw*16 + i*4 + (lane>>4); LDS phys chunk = lane&15
    // holds logical chunk (lane&15) ^ (row&15), row&15 = i*4 + (lane>>4).
    const int kw = wave & 1;
    const f16* kbase = Kc + (long)(h * 2048 + key0 + kw * 16 + (lane >> 4)) * 128;
    // V staging (waves 2,3): phys cs = lane&3 holds logical (lane&3) ^ ((lane>>3)&3)
    const int tb = wave & 1;
    const f16* vbase = Vtg + (long)((tb * 16 + h) * 64 + (lane >> 2)) * 2048 + key0
                       + ((lane & 3) ^ ((lane >> 3) & 3)) * 8;

    auto stage = [&](int kt, int buf) {              // exactly 4 GLD16 per wave
        if (wave < 2) {
            f16* l = &KsC[buf][0][0] + kw * 2048;
            #pragma unroll
            for (int i = 0; i < 4; ++i) {
                const int gch = ((lane & 15) ^ ((i << 2) | (lane >> 4))) << 3;   // global chunk (halves)
                GLD16(kbase + (long)kt * 4096 + i * 512 + gch, l + i * 512);
            }
        } else {
            const f16* g = vbase + kt * 32;
            f16* l = &Vts[buf][tb][0][0];
            #pragma unroll
            for (int i = 0; i < 4; ++i) GLD16(g + (long)i * 16 * 2048, l + i * 512);
        }
    };

    const f16* VtsF = &Vts[0][0][0][0];              // per-buf stride 4096 halves
    const f16x8 ones8 = {(f16)1.f,(f16)1.f,(f16)1.f,(f16)1.f,(f16)1.f,(f16)1.f,(f16)1.f,(f16)1.f};

    stage(0, 0);
    stage(1, 1);
    int cur = 0, nx2 = 2;
    for (int kt = 0; kt < nt; ++kt) {
        if (kt == nt - 1) asm volatile("s_waitcnt vmcnt(0)" ::: "memory");
        else              asm volatile("s_waitcnt vmcnt(4)" ::: "memory");
        __builtin_amdgcn_s_barrier();
        __builtin_amdgcn_sched_barrier(0);
        if (kt + 2 < nt) stage(kt + 2, nx2);

        // ---- dS = [K1|-K0]·[Q1|Q0]: S[key=(r&3)+8(r>>2)+4hi][q], per q-half g ----
        f16x8 pf0[2][2];                             // [g][keyh] batch0 prob fragments
        #pragma unroll
        for (int g = 0; g < 2; ++g) {
            f32x16 S = {};
            __builtin_amdgcn_s_setprio(1);
            #pragma unroll
            for (int s2 = 0; s2 < 8; ++s2) {
                f16x8 a = *(const f16x8*)&KsC[cur][l31][(((s2 * 2 + hi) ^ kch) << 3)];
                S = MFMA32(a, qfr[g][s2], S);
            }
            __builtin_amdgcn_s_setprio(0);

            unsigned pk[8];
            #pragma unroll
            for (int p = 0; p < 8; ++p) {
                float e0 = __builtin_amdgcn_exp2f(S[2 * p]);
                float e1 = __builtin_amdgcn_exp2f(S[2 * p + 1]);
                float pa = __builtin_amdgcn_rcpf(1.0f + e0);   // e=inf -> p=0 (safe)
                float pb = __builtin_amdgcn_rcpf(1.0f + e1);
                auto h2 = __builtin_amdgcn_cvt_pkrtz(pa, pb);
                pk[p] = __builtin_bit_cast(unsigned, h2);
            }
            #pragma unroll
            for (int keyh = 0; keyh < 2; ++keyh) {
                unsigned a0 = pk[4 * keyh + 0], b0 = pk[4 * keyh + 2];
                unsigned a1 = pk[4 * keyh + 1], b1 = pk[4 * keyh + 3];
                asm("v_permlane32_swap_b32 %0, %1" : "+v"(a0), "+v"(b0));
                asm("v_permlane32_swap_b32 %0, %1" : "+v"(a1), "+v"(b1));
                union { unsigned u[4]; f16x8 v; } m;
                m.u[0] = a0; m.u[1] = a1; m.u[2] = b0; m.u[3] = b1;
                pf0[g][keyh] = m.v;
            }
        }

        // ---- PV: O^T[hd][q] += V^T[hd][key] * P^T[key][q]; V frags shared across g ----
        __builtin_amdgcn_s_setprio(1);
        #pragma unroll
        for (int pb = 0; pb < 2; ++pb)
            #pragma unroll
            for (int keyh = 0; keyh < 2; ++keyh) {
                f16x8 vf[2];
                #pragma unroll
                for (int hdh = 0; hdh < 2; ++hdh)
                    vf[hdh] = *(const f16x8*)&VtsF[cur * 4096 + pb * 2048 + hdh * 1024
                                                   + l31 * 32 + (((keyh * 2 + hi) ^ vcb) << 3)];
                #pragma unroll
                for (int g = 0; g < 2; ++g) {
                    const f16x8 pfr = pb ? (ones8 - pf0[g][keyh]) : pf0[g][keyh];
                    #pragma unroll
                    for (int hdh = 0; hdh < 2; ++hdh)
                        acc[pb][g][hdh] = MFMA32(vf[hdh], pfr, acc[pb][g][hdh]);
                }
            }
        __builtin_amdgcn_s_setprio(0);

        cur = cur == 2 ? 0 : cur + 1;
        nx2 = nx2 == 2 ? 0 : nx2 + 1;
    }

    // D[row=hd=hdh*32+gg*8+hi*4+r2][col=q=qr+g*32+l31] -> f16x4 stores along hd
    #pragma unroll
    for (int pb = 0; pb < 2; ++pb)
        #pragma unroll
        for (int g = 0; g < 2; ++g)
            #pragma unroll
            for (int hdh = 0; hdh < 2; ++hdh)
                #pragma unroll
                for (int gg = 0; gg < 4; ++gg) {
                    f16x4 ov;
                    #pragma unroll
                    for (int r2 = 0; r2 < 4; ++r2) ov[r2] = (f16)acc[pb][g][hdh][gg * 4 + r2];
                    *(f16x4*)(vals + (long)(pb * 2048 + qr + g * 32 + l31) * 1024
                              + h * 64 + hdh * 32 + gg * 8 + hi * 4) = ov;
                }
}

extern "C" void kernel_launch(void* const* d_in, const int* in_sizes, int n_in,
                              void* d_out, int out_size, void* d_ws, size_t ws_size,
                              hipStream_t stream) {
    const float* x  = (const float*)d_in[0];
    const float* wq = (const float*)d_in[1];
    const float* wk = (const float*)d_in[2];
    const float* wv = (const float*)d_in[3];
    const float* wo = (const float*)d_in[4];

    char* ws = (char*)d_ws;
    f16* xh    = (f16*)(ws);                   // 8 MiB; dead after QKV gemm -> reused as vals0
    f16* wqT   = (f16*)(ws + 8388608);         // wqT,wkT,wvT contiguous = fused [3072][1024]
    f16* wkT   = (f16*)(ws + 10485760);
    f16* wvT   = (f16*)(ws + 12582912);
    f16* woT   = (f16*)(ws + 14680064);
    f16* Qc    = (f16*)(ws + 16777216);        // [16][2048][128] concat: d<64=b1, d>=64=b0
    f16* Kc    = (f16*)(ws + 25165824);        // [16][2048][128] concat: [K1 | -K0]
    f16* Vtg   = (f16*)(ws + 33554432);        // [2][16][64][2048]
    f16* vals1 = (f16*)(ws + 41943040);
    f16* vals2 = (f16*)(ws + 50331648);
    f16* vals3 = (f16*)(ws + 58720256);
    f16* vals0 = xh;
    (void)in_sizes; (void)n_in; (void)out_size; (void)ws_size;

    prep<<<5120, 256, 0, stream>>>(x, wq, wk, wv, wo, xh, wqT, wkT, wvT, woT);

    gemm_qkv<<<dim3(32, 24), 256, 0, stream>>>(xh, wqT, Qc, Kc, Vtg);

    attention_kernel<<<512, 256, 0, stream>>>(Qc, Kc, Vtg, vals0, vals1, vals2, vals3);

    gemm_out<4><<<dim3(64, 8), 256, 0, stream>>>(vals0, vals1, vals2, vals3, woT, (float*)d_out);
}